// Round 2
// baseline (6799.032 us; speedup 1.0000x reference)
//
#include <hip/hip_runtime.h>
#include <math.h>

// ---------------------------------------------------------------------------
// RNN knowledge-tracing model, MI355X (gfx950).
// B=64, T=200, SKILLS=1024, C=256, H=1024.  ALL external I/O is fp32.
// Internal compute uses bf16 MFMA with fp32 accumulation.
// Phases:
//   cvt : fp32->bf16 for q_hot, next_q_hot, W_kc, W_ih, W_hh, W_state
//   A1a: kc_vec[12800,512]  = mask-scatter(q_hot @ W_kc^T + b_kc)   (bf16 ws)
//   A1b: nk[12800,256]      = next_q_hot @ W_kc^T + b_kc            (fp32 ws)
//   A2 : gx[t*64+b,4096]    = kc_vec @ W_ih^T + b_ih + b_hh         (bf16 ws)
//   B  : LSTM scan, 200 steps, persistent 256-block kernel w/ grid barrier
//   C  : stu[b*200+t,256]   = h_seq @ W_state^T + b_state           (fp32 out)
//   D  : res[b*200+t]       = sum_c (stu-nk)*nk*W_out + b_out       (fp32 out)
// ---------------------------------------------------------------------------

typedef unsigned short u16;
typedef __bf16 bf16x8 __attribute__((ext_vector_type(8)));
typedef float floatx4 __attribute__((ext_vector_type(4)));

__device__ __forceinline__ float bf2f(u16 h) {
  unsigned int u = ((unsigned int)h) << 16;
  float f;
  __builtin_memcpy(&f, &u, 4);
  return f;
}
__device__ __forceinline__ u16 f2bf(float f) {
  unsigned int u;
  __builtin_memcpy(&u, &f, 4);
  u += 0x7FFFu + ((u >> 16) & 1u);  // RNE
  return (u16)(u >> 16);
}
__device__ __forceinline__ float sigm(float x) { return 1.0f / (1.0f + __expf(-x)); }

// --- fp32 -> bf16 convert, float4 vectorized; exact grid (n % 1024 == 0) ---
__global__ void cvt_kernel(const float* __restrict__ in, u16* __restrict__ out) {
  const int i = blockIdx.x * 256 + threadIdx.x;
  const float4 v = ((const float4*)in)[i];
  ushort4 o;
  o.x = f2bf(v.x);
  o.y = f2bf(v.y);
  o.z = f2bf(v.z);
  o.w = f2bf(v.w);
  ((ushort4*)out)[i] = o;
}

// ---------------------------------------------------------------------------
// Generic 128x128-tile bf16 GEMM, C = A[M,K] @ B[N,K]^T, epilogue functor.
// m97 structure: global_load_lds width=16 staging, 4 waves 2x2, 4x4 accs of
// 16x16x32 MFMA. M%128==0, N%128==0, K%32==0 assumed (true for all uses).
// ---------------------------------------------------------------------------
template <class Epi>
__global__ __launch_bounds__(256, 2) void gemm_bt(const u16* __restrict__ A,
                                                  const u16* __restrict__ B,
                                                  int M, int N, int K, Epi epi) {
  __shared__ u16 As[128 * 32];
  __shared__ u16 Bs[128 * 32];
  const int tid = threadIdx.x;
  const int w = tid >> 6, lane = tid & 63;
  const int wm = w & 1, wn = w >> 1;
  const int bm = blockIdx.x * 128, bn = blockIdx.y * 128;
  const int lrow = lane & 15, lk8 = (lane >> 4) * 8;
  const int srow = lane >> 2;        // staging: row within 16-row segment
  const int skc = (lane & 3) * 8;    // staging: k chunk (8 bf16 = 16B)

  floatx4 acc[4][4] = {};

  for (int k0 = 0; k0 < K; k0 += 32) {
#pragma unroll
    for (int r = 0; r < 2; ++r) {
      const int seg = w * 2 + r;  // 8 segments of 16 rows x 32 k
      const int row = seg * 16 + srow;
      __builtin_amdgcn_global_load_lds(
          (const __attribute__((address_space(1))) unsigned int*)(A + (size_t)(bm + row) * K + k0 + skc),
          (__attribute__((address_space(3))) unsigned int*)(As + seg * 512), 16, 0, 0);
      __builtin_amdgcn_global_load_lds(
          (const __attribute__((address_space(1))) unsigned int*)(B + (size_t)(bn + row) * K + k0 + skc),
          (__attribute__((address_space(3))) unsigned int*)(Bs + seg * 512), 16, 0, 0);
    }
    __syncthreads();

    bf16x8 af[4], bfr[4];
#pragma unroll
    for (int i = 0; i < 4; ++i) {
      af[i] = *(const bf16x8*)(As + (wm * 64 + i * 16 + lrow) * 32 + lk8);
      bfr[i] = *(const bf16x8*)(Bs + (wn * 64 + i * 16 + lrow) * 32 + lk8);
    }
#pragma unroll
    for (int i = 0; i < 4; ++i)
#pragma unroll
      for (int j = 0; j < 4; ++j)
        acc[i][j] = __builtin_amdgcn_mfma_f32_16x16x32_bf16(af[i], bfr[j], acc[i][j], 0, 0, 0);
    __syncthreads();
  }

  // C/D layout: col = lane&15, row = (lane>>4)*4 + reg  [verified m89/m91]
  const int rbase = bm + wm * 64 + (lane >> 4) * 4;
  const int cbase = bn + wn * 64 + lrow;
#pragma unroll
  for (int i = 0; i < 4; ++i)
#pragma unroll
    for (int j = 0; j < 4; ++j)
#pragma unroll
      for (int r = 0; r < 4; ++r)
        epi(rbase + i * 16 + r, cbase + j * 16, acc[i][j][r]);
}

// --- epilogues --------------------------------------------------------------
struct EpiKcVec {  // rows are b*200+t; scatter into [row][512] by result mask
  const float* bkc;
  const int* result;
  u16* kcv;
  __device__ void operator()(int row, int col, float v) const {
    v += bkc[col];
    const int off = (result[row] == 1) ? 0 : 256;
    const size_t base = (size_t)row * 512;
    kcv[base + off + col] = f2bf(v);
    kcv[base + (256 - off) + col] = 0;  // zero half
  }
};
struct EpiNk {
  const float* bkc;
  float* nk;
  __device__ void operator()(int row, int col, float v) const {
    nk[(size_t)row * 256 + col] = v + bkc[col];
  }
};
struct EpiGx {  // input row = b*200+t -> store t-major (t*64+b), bf16
  const float* bih;
  const float* bhh;
  u16* gx;
  __device__ void operator()(int row, int col, float v) const {
    v += bih[col] + bhh[col];
    const int b = row / 200, t = row - b * 200;
    gx[(size_t)(t * 64 + b) * 4096 + col] = f2bf(v);
  }
};
struct EpiStu {  // input row = t*64+b -> store fp32 at (b*200+t)*256+col
  const float* bst;
  float* out;
  __device__ void operator()(int row, int col, float v) const {
    v += bst[col];
    const int b = row & 63, t = row >> 6;
    out[(size_t)(b * 200 + t) * 256 + col] = v;
  }
};

// ---------------------------------------------------------------------------
// init: zero h frame 0 (64x1024 bf16 = 128KB) + barrier counters
// ---------------------------------------------------------------------------
__global__ void init_kernel(u16* hseq, unsigned* bar) {
  const int i = blockIdx.x * 256 + threadIdx.x;  // 64 blocks -> 16384 threads
  ((unsigned long long*)hseq)[i] = 0ULL;
  if (i == 0) {
    bar[0] = 0u;   // count
    bar[32] = 0u;  // generation (separate cacheline)
  }
}

// ---------------------------------------------------------------------------
// device-scope grid barrier (sense via monotonic generation counter).
// All 256 blocks are simultaneously resident (grid == CU count, 1 block/CU),
// so spinning is deadlock-free. Agent-scope atomics/fences give cross-XCD
// visibility of the plain h stores (G16).
// ---------------------------------------------------------------------------
__device__ __forceinline__ void grid_barrier(unsigned* bar, unsigned nb) {
  __threadfence();  // release our h stores to agent scope
  __syncthreads();
  if (threadIdx.x == 0) {
    unsigned* cnt = bar;
    unsigned* gen = bar + 32;
    const unsigned g = __hip_atomic_load(gen, __ATOMIC_RELAXED, __HIP_MEMORY_SCOPE_AGENT);
    if (__hip_atomic_fetch_add(cnt, 1u, __ATOMIC_ACQ_REL, __HIP_MEMORY_SCOPE_AGENT) == nb - 1u) {
      __hip_atomic_store(cnt, 0u, __ATOMIC_RELAXED, __HIP_MEMORY_SCOPE_AGENT);
      __hip_atomic_fetch_add(gen, 1u, __ATOMIC_ACQ_REL, __HIP_MEMORY_SCOPE_AGENT);
    } else {
      while (__hip_atomic_load(gen, __ATOMIC_ACQUIRE, __HIP_MEMORY_SCOPE_AGENT) == g)
        __builtin_amdgcn_s_sleep(1);
    }
  }
  __syncthreads();
}

// ---------------------------------------------------------------------------
// LSTM scan. 256 blocks = 4 batch-groups x 64 col-groups; block owns 16
// batches x 16 h-cols. Wave w (0..3) = gate w; its W_hh slice (16 rows x
// 1024 K) lives in registers as 32 B-fragments for the whole kernel.
// Per step: stage h[t] slice (16x1024) to LDS, acc init from gx, 32 MFMAs,
// gate math (c in a register/thread), write h[t+1], grid barrier.
// ---------------------------------------------------------------------------
__global__ __launch_bounds__(256, 1) void lstm_scan(const u16* __restrict__ Whh,
                                                    const u16* __restrict__ gx,
                                                    u16* __restrict__ hseq,
                                                    unsigned* bar) {
  __shared__ u16 Ab[16 * 1032];   // +8 pad: frag-read 2-way bank alias (free)
  __shared__ float gbuf[4 * 256];
  const int tid = threadIdx.x;
  const int w = tid >> 6;         // gate index (torch order i,f,g,o)
  const int lane = tid & 63;
  const int lrow = lane & 15;
  const int lk8 = (lane >> 4) * 8;
  const int gb = blockIdx.x >> 6;
  const int gn = blockIdx.x & 63;
  const int bb = gb * 16;
  const int j0 = gn * 16;

  // B-fragments: W_hh[w*1024 + j0 + n][k], n = lane&15 -> 128 VGPRs, loaded once
  bf16x8 bfrag[32];
  {
    const u16* wp = Whh + (size_t)(w * 1024 + j0 + lrow) * 1024 + lk8;
#pragma unroll
    for (int ks = 0; ks < 32; ++ks) bfrag[ks] = *(const bf16x8*)(wp + ks * 32);
  }

  float c_state = 0.0f;
  const int um = tid >> 4, un = tid & 15;  // update-phase (batch, col) mapping

  for (int t = 0; t < 200; ++t) {
    // stage h[t] rows bb..bb+15, all 1024 cols -> LDS (32KB), contiguous global
    {
      const u16* hs = hseq + (size_t)t * 65536 + (size_t)bb * 1024;
#pragma unroll
      for (int jj = 0; jj < 8; ++jj) {
        const int ch = jj * 256 + tid;       // 2048 chunks of 8 bf16
        const int row = ch >> 7;
        const int cc = (ch & 127) * 8;
        *(bf16x8*)(Ab + row * 1032 + cc) = *(const bf16x8*)(hs + row * 1024 + cc);
      }
    }
    __syncthreads();

    // acc init = gx (includes b_ih+b_hh); D layout col=lane&15, row=(lane>>4)*4+r
    floatx4 acc;
    {
      const u16* gp = gx + (size_t)(t * 64 + bb + (lane >> 4) * 4) * 4096 + w * 1024 + j0 + lrow;
      acc[0] = bf2f(gp[0]);
      acc[1] = bf2f(gp[4096]);
      acc[2] = bf2f(gp[8192]);
      acc[3] = bf2f(gp[12288]);
    }
#pragma unroll
    for (int ks = 0; ks < 32; ++ks) {
      bf16x8 a = *(const bf16x8*)(Ab + lrow * 1032 + ks * 32 + lk8);
      acc = __builtin_amdgcn_mfma_f32_16x16x32_bf16(a, bfrag[ks], acc, 0, 0, 0);
    }
    {
      const int mrow = (lane >> 4) * 4;
#pragma unroll
      for (int r = 0; r < 4; ++r) gbuf[w * 256 + (mrow + r) * 16 + lrow] = acc[r];
    }
    __syncthreads();

    const float gi = gbuf[tid];
    const float gf = gbuf[256 + tid];
    const float gg = gbuf[512 + tid];
    const float go = gbuf[768 + tid];
    c_state = sigm(gf) * c_state + sigm(gi) * tanhf(gg);
    const float h = sigm(go) * tanhf(c_state);
    hseq[(size_t)(t + 1) * 65536 + (size_t)(bb + um) * 1024 + j0 + un] = f2bf(h);

    grid_barrier(bar, 256);
  }
}

// ---------------------------------------------------------------------------
// res[b*200+t] = sum_c (stu-nk)*nk*W_out[c] + b_out ; one wave per row.
// stu is read from d_out (fp32), nk from ws (fp32).
// ---------------------------------------------------------------------------
__global__ void res_kernel(const float* __restrict__ stu, const float* __restrict__ nk,
                           const float* __restrict__ Wout, const float* __restrict__ bout,
                           float* __restrict__ res) {
  const int row = blockIdx.x * 4 + (threadIdx.x >> 6);
  const int lane = threadIdx.x & 63;
  const float* sp = stu + (size_t)row * 256;
  const float* np = nk + (size_t)row * 256;
  float s = 0.0f;
#pragma unroll
  for (int j = 0; j < 4; ++j) {
    const int c = j * 64 + lane;
    const float nv = np[c];
    s += (sp[c] - nv) * nv * Wout[c];
  }
#pragma unroll
  for (int o = 32; o > 0; o >>= 1) s += __shfl_down(s, o, 64);
  if (lane == 0) res[row] = s + bout[0];
}

// ---------------------------------------------------------------------------
extern "C" void kernel_launch(void* const* d_in, const int* in_sizes, int n_in,
                              void* d_out, int out_size, void* d_ws, size_t ws_size,
                              hipStream_t stream) {
  const float* q_hot = (const float*)d_in[0];
  const int* result = (const int*)d_in[1];
  const float* next_q = (const float*)d_in[2];
  // d_in[3] = concept_num (unused, compile-time constant 256)
  const float* W_kc = (const float*)d_in[4];
  const float* b_kc = (const float*)d_in[5];
  const float* W_ih = (const float*)d_in[6];
  const float* W_hh = (const float*)d_in[7];
  const float* b_ih = (const float*)d_in[8];
  const float* b_hh = (const float*)d_in[9];
  const float* W_state = (const float*)d_in[10];
  const float* b_state = (const float*)d_in[11];
  const float* W_out = (const float*)d_in[12];
  const float* b_out = (const float*)d_in[13];

  float* out_res = (float*)d_out;       // 12800 fp32
  float* out_stu = out_res + 12800;     // 12800*256 fp32

  char* ws = (char*)d_ws;
  u16* kcv = (u16*)(ws);                        // 12800*512 bf16  = 13,107,200 B
  float* nk = (float*)(ws + 13107200);          // 12800*256 fp32  = 13,107,200 B
  u16* hseq = (u16*)(ws + 26214400);            // 201*65536 bf16  = 26,345,472 B
  u16* Whh_bf = (u16*)(ws + 52559872);          // 4096*1024 bf16  =  8,388,608 B
  u16* Wih_bf = (u16*)(ws + 60948480);          // 4096*512 bf16   =  4,194,304 B
  u16* Wkc_bf = (u16*)(ws + 65142784);          // 256*1024 bf16   =    524,288 B
  u16* Wst_bf = (u16*)(ws + 65667072);          // 256*1024 bf16   =    524,288 B
  unsigned* bar = (unsigned*)(ws + 66191360);   // 1024 B
  u16* gx = (u16*)(ws + 66192384);              // 12800*4096 bf16 = 104,857,600 B
  // q_bf/nq_bf alias the gx region (dead before gx is written)
  u16* q_bf = gx;                               // 12800*1024 bf16 = 26,214,400 B
  u16* nq_bf = gx + 13107200;                   // 12800*1024 bf16
  // total ws footprint: 171,049,984 B

  // fp32 -> bf16 conversions
  cvt_kernel<<<dim3(12800), 256, 0, stream>>>(q_hot, q_bf);
  cvt_kernel<<<dim3(12800), 256, 0, stream>>>(next_q, nq_bf);
  cvt_kernel<<<dim3(256), 256, 0, stream>>>(W_kc, Wkc_bf);
  cvt_kernel<<<dim3(2048), 256, 0, stream>>>(W_ih, Wih_bf);
  cvt_kernel<<<dim3(4096), 256, 0, stream>>>(W_hh, Whh_bf);
  cvt_kernel<<<dim3(256), 256, 0, stream>>>(W_state, Wst_bf);

  init_kernel<<<dim3(64), 256, 0, stream>>>(hseq, bar);
  gemm_bt<EpiKcVec><<<dim3(100, 2), 256, 0, stream>>>(q_bf, Wkc_bf, 12800, 256, 1024,
                                                      EpiKcVec{b_kc, result, kcv});
  gemm_bt<EpiNk><<<dim3(100, 2), 256, 0, stream>>>(nq_bf, Wkc_bf, 12800, 256, 1024,
                                                   EpiNk{b_kc, nk});
  gemm_bt<EpiGx><<<dim3(100, 32), 256, 0, stream>>>(kcv, Wih_bf, 12800, 4096, 512,
                                                    EpiGx{b_ih, b_hh, gx});
  lstm_scan<<<dim3(256), 256, 0, stream>>>(Whh_bf, gx, hseq, bar);
  gemm_bt<EpiStu><<<dim3(100, 2), 256, 0, stream>>>(hseq + 65536, Wst_bf, 12800, 256, 1024,
                                                    EpiStu{b_state, out_stu});
  res_kernel<<<dim3(3200), 256, 0, stream>>>(out_stu, nk, W_out, b_out, out_res);
}

// Round 3
// 5012.803 us; speedup vs baseline: 1.3563x; 1.3563x over previous
//
#include <hip/hip_runtime.h>
#include <math.h>

// ---------------------------------------------------------------------------
// RNN knowledge-tracing model, MI355X (gfx950).
// B=64, T=200, SKILLS=1024, C=256, H=1024.  ALL external I/O is fp32.
// Internal compute uses bf16 MFMA with fp32 accumulation.
// Round 3 change: LSTM grid barrier = per-block flag array (no single-counter
// fetch_add serialization), relaxed polls + single acquire, gx prefetch
// under the spin. Everything else preserved from the passing round-2 kernel.
// ---------------------------------------------------------------------------

typedef unsigned short u16;
typedef __bf16 bf16x8 __attribute__((ext_vector_type(8)));
typedef float floatx4 __attribute__((ext_vector_type(4)));

__device__ __forceinline__ float bf2f(u16 h) {
  unsigned int u = ((unsigned int)h) << 16;
  float f;
  __builtin_memcpy(&f, &u, 4);
  return f;
}
__device__ __forceinline__ u16 f2bf(float f) {
  unsigned int u;
  __builtin_memcpy(&u, &f, 4);
  u += 0x7FFFu + ((u >> 16) & 1u);  // RNE
  return (u16)(u >> 16);
}
__device__ __forceinline__ float sigm(float x) { return 1.0f / (1.0f + __expf(-x)); }

// --- fp32 -> bf16 convert, float4 vectorized; exact grid (n % 1024 == 0) ---
__global__ void cvt_kernel(const float* __restrict__ in, u16* __restrict__ out) {
  const int i = blockIdx.x * 256 + threadIdx.x;
  const float4 v = ((const float4*)in)[i];
  ushort4 o;
  o.x = f2bf(v.x);
  o.y = f2bf(v.y);
  o.z = f2bf(v.z);
  o.w = f2bf(v.w);
  ((ushort4*)out)[i] = o;
}

// ---------------------------------------------------------------------------
// Generic 128x128-tile bf16 GEMM, C = A[M,K] @ B[N,K]^T, epilogue functor.
// ---------------------------------------------------------------------------
template <class Epi>
__global__ __launch_bounds__(256, 2) void gemm_bt(const u16* __restrict__ A,
                                                  const u16* __restrict__ B,
                                                  int M, int N, int K, Epi epi) {
  __shared__ u16 As[128 * 32];
  __shared__ u16 Bs[128 * 32];
  const int tid = threadIdx.x;
  const int w = tid >> 6, lane = tid & 63;
  const int wm = w & 1, wn = w >> 1;
  const int bm = blockIdx.x * 128, bn = blockIdx.y * 128;
  const int lrow = lane & 15, lk8 = (lane >> 4) * 8;
  const int srow = lane >> 2;        // staging: row within 16-row segment
  const int skc = (lane & 3) * 8;    // staging: k chunk (8 bf16 = 16B)

  floatx4 acc[4][4] = {};

  for (int k0 = 0; k0 < K; k0 += 32) {
#pragma unroll
    for (int r = 0; r < 2; ++r) {
      const int seg = w * 2 + r;  // 8 segments of 16 rows x 32 k
      const int row = seg * 16 + srow;
      __builtin_amdgcn_global_load_lds(
          (const __attribute__((address_space(1))) unsigned int*)(A + (size_t)(bm + row) * K + k0 + skc),
          (__attribute__((address_space(3))) unsigned int*)(As + seg * 512), 16, 0, 0);
      __builtin_amdgcn_global_load_lds(
          (const __attribute__((address_space(1))) unsigned int*)(B + (size_t)(bn + row) * K + k0 + skc),
          (__attribute__((address_space(3))) unsigned int*)(Bs + seg * 512), 16, 0, 0);
    }
    __syncthreads();

    bf16x8 af[4], bfr[4];
#pragma unroll
    for (int i = 0; i < 4; ++i) {
      af[i] = *(const bf16x8*)(As + (wm * 64 + i * 16 + lrow) * 32 + lk8);
      bfr[i] = *(const bf16x8*)(Bs + (wn * 64 + i * 16 + lrow) * 32 + lk8);
    }
#pragma unroll
    for (int i = 0; i < 4; ++i)
#pragma unroll
      for (int j = 0; j < 4; ++j)
        acc[i][j] = __builtin_amdgcn_mfma_f32_16x16x32_bf16(af[i], bfr[j], acc[i][j], 0, 0, 0);
    __syncthreads();
  }

  // C/D layout: col = lane&15, row = (lane>>4)*4 + reg  [verified m89/m91]
  const int rbase = bm + wm * 64 + (lane >> 4) * 4;
  const int cbase = bn + wn * 64 + lrow;
#pragma unroll
  for (int i = 0; i < 4; ++i)
#pragma unroll
    for (int j = 0; j < 4; ++j)
#pragma unroll
      for (int r = 0; r < 4; ++r)
        epi(rbase + i * 16 + r, cbase + j * 16, acc[i][j][r]);
}

// --- epilogues --------------------------------------------------------------
struct EpiKcVec {  // rows are b*200+t; scatter into [row][512] by result mask
  const float* bkc;
  const int* result;
  u16* kcv;
  __device__ void operator()(int row, int col, float v) const {
    v += bkc[col];
    const int off = (result[row] == 1) ? 0 : 256;
    const size_t base = (size_t)row * 512;
    kcv[base + off + col] = f2bf(v);
    kcv[base + (256 - off) + col] = 0;  // zero half
  }
};
struct EpiNk {
  const float* bkc;
  float* nk;
  __device__ void operator()(int row, int col, float v) const {
    nk[(size_t)row * 256 + col] = v + bkc[col];
  }
};
struct EpiGx {  // input row = b*200+t -> store t-major (t*64+b), bf16
  const float* bih;
  const float* bhh;
  u16* gx;
  __device__ void operator()(int row, int col, float v) const {
    v += bih[col] + bhh[col];
    const int b = row / 200, t = row - b * 200;
    gx[(size_t)(t * 64 + b) * 4096 + col] = f2bf(v);
  }
};
struct EpiStu {  // input row = t*64+b -> store fp32 at (b*200+t)*256+col
  const float* bst;
  float* out;
  __device__ void operator()(int row, int col, float v) const {
    v += bst[col];
    const int b = row & 63, t = row >> 6;
    out[(size_t)(b * 200 + t) * 256 + col] = v;
  }
};

// ---------------------------------------------------------------------------
// init: zero h frame 0 (64x1024 bf16 = 128KB) + 256 barrier flags
// ---------------------------------------------------------------------------
__global__ void init_kernel(u16* hseq, unsigned* flags) {
  const int i = blockIdx.x * 256 + threadIdx.x;  // 64 blocks -> 16384 threads
  ((unsigned long long*)hseq)[i] = 0ULL;
  if (blockIdx.x == 0) flags[threadIdx.x] = 0u;
}

// ---------------------------------------------------------------------------
// LSTM scan. 256 blocks = 4 batch-groups x 64 col-groups; block owns 16
// batches x 16 h-cols. Wave w (0..3) = gate w; its W_hh slice (16 rows x
// 1024 K) lives in registers as 32 MFMA B-fragments for the whole kernel.
// Per step: stage h[t] slice (16x1024) to LDS, acc init from gx, 32 MFMAs,
// gate math (c in a register/thread), write h[t+1], flag-array grid barrier:
//   publish: plain h stores -> __threadfence (wbl2, proven in round 2) ->
//            __syncthreads -> relaxed agent store flags[bid]=t+1
//   wait:    wave 0 polls all 256 flags (4 coalesced relaxed loads/lane),
//            one acquire load (buffer_inv) on exit, __syncthreads.
// gx for step t+1 is prefetched into registers under the spin (h-independent).
// ---------------------------------------------------------------------------
__global__ __launch_bounds__(256, 1) void lstm_scan(const u16* __restrict__ Whh,
                                                    const u16* __restrict__ gx,
                                                    u16* __restrict__ hseq,
                                                    unsigned* __restrict__ flags) {
  __shared__ u16 Ab[16 * 1032];   // +8 pad: frag-read 2-way bank alias (free)
  __shared__ float gbuf[4 * 256];
  const int tid = threadIdx.x;
  const int w = tid >> 6;         // gate index (torch order i,f,g,o)
  const int lane = tid & 63;
  const int lrow = lane & 15;
  const int lk8 = (lane >> 4) * 8;
  const int gb = blockIdx.x >> 6;
  const int gn = blockIdx.x & 63;
  const int bb = gb * 16;
  const int j0 = gn * 16;

  // B-fragments: W_hh[w*1024 + j0 + n][k], n = lane&15 -> 128 VGPRs, loaded once
  bf16x8 bfrag[32];
  {
    const u16* wp = Whh + (size_t)(w * 1024 + j0 + lrow) * 1024 + lk8;
#pragma unroll
    for (int ks = 0; ks < 32; ++ks) bfrag[ks] = *(const bf16x8*)(wp + ks * 32);
  }

  float c_state = 0.0f;
  const int um = tid >> 4, un = tid & 15;  // update-phase (batch, col) mapping

  // gx fetch: 4 values/thread (batch rows (lane>>4)*4+r, gate w, col j0+lrow)
  const u16* gxb = gx + (size_t)(bb + (lane >> 4) * 4) * 4096 + w * 1024 + j0 + lrow;
  u16 gcur[4];
  {
    const u16* gp = gxb;  // t = 0
    gcur[0] = gp[0];
    gcur[1] = gp[4096];
    gcur[2] = gp[8192];
    gcur[3] = gp[12288];
  }

  for (int t = 0; t < 200; ++t) {
    // stage h[t] rows bb..bb+15, all 1024 cols -> LDS (32KB), contiguous global
    {
      const u16* hs = hseq + (size_t)t * 65536 + (size_t)bb * 1024;
#pragma unroll
      for (int jj = 0; jj < 8; ++jj) {
        const int ch = jj * 256 + tid;       // 2048 chunks of 8 bf16
        const int row = ch >> 7;
        const int cc = (ch & 127) * 8;
        *(bf16x8*)(Ab + row * 1032 + cc) = *(const bf16x8*)(hs + row * 1024 + cc);
      }
    }
    __syncthreads();

    // acc init = gx (includes b_ih+b_hh); D layout col=lane&15, row=(lane>>4)*4+r
    floatx4 acc;
    acc[0] = bf2f(gcur[0]);
    acc[1] = bf2f(gcur[1]);
    acc[2] = bf2f(gcur[2]);
    acc[3] = bf2f(gcur[3]);
#pragma unroll
    for (int ks = 0; ks < 32; ++ks) {
      bf16x8 a = *(const bf16x8*)(Ab + lrow * 1032 + ks * 32 + lk8);
      acc = __builtin_amdgcn_mfma_f32_16x16x32_bf16(a, bfrag[ks], acc, 0, 0, 0);
    }
    {
      const int mrow = (lane >> 4) * 4;
#pragma unroll
      for (int r = 0; r < 4; ++r) gbuf[w * 256 + (mrow + r) * 16 + lrow] = acc[r];
    }
    __syncthreads();

    const float gi = gbuf[tid];
    const float gf = gbuf[256 + tid];
    const float gg = gbuf[512 + tid];
    const float go = gbuf[768 + tid];
    c_state = sigm(gf) * c_state + sigm(gi) * tanhf(gg);
    const float h = sigm(go) * tanhf(c_state);
    hseq[(size_t)(t + 1) * 65536 + (size_t)(bb + um) * 1024 + j0 + un] = f2bf(h);

    // ---- publish ----
    __threadfence();       // agent-scope release of the plain h stores
    __syncthreads();       // all threads' stores fenced before the flag
    if (tid == 0)
      __hip_atomic_store(&flags[blockIdx.x], (unsigned)(t + 1), __ATOMIC_RELAXED,
                         __HIP_MEMORY_SCOPE_AGENT);

    // ---- prefetch gx for t+1 while the barrier resolves ----
    if (t < 199) {
      const u16* gp = gxb + (size_t)(t + 1) * 64 * 4096;
      gcur[0] = gp[0];
      gcur[1] = gp[4096];
      gcur[2] = gp[8192];
      gcur[3] = gp[12288];
    }

    // ---- wait: wave 0 polls all 256 flags, no RMW, relaxed ----
    if (tid < 64) {
      const unsigned tgt = (unsigned)(t + 1);
      for (;;) {
        const unsigned v0 = __hip_atomic_load(&flags[lane], __ATOMIC_RELAXED, __HIP_MEMORY_SCOPE_AGENT);
        const unsigned v1 = __hip_atomic_load(&flags[64 + lane], __ATOMIC_RELAXED, __HIP_MEMORY_SCOPE_AGENT);
        const unsigned v2 = __hip_atomic_load(&flags[128 + lane], __ATOMIC_RELAXED, __HIP_MEMORY_SCOPE_AGENT);
        const unsigned v3 = __hip_atomic_load(&flags[192 + lane], __ATOMIC_RELAXED, __HIP_MEMORY_SCOPE_AGENT);
        const bool ok = (v0 >= tgt) & (v1 >= tgt) & (v2 >= tgt) & (v3 >= tgt);
        if (__all(ok)) break;
        __builtin_amdgcn_s_sleep(2);
      }
      // single acquire (buffer_inv) to make all blocks' h stores visible
      (void)__hip_atomic_load(&flags[lane], __ATOMIC_ACQUIRE, __HIP_MEMORY_SCOPE_AGENT);
    }
    __syncthreads();
  }
}

// ---------------------------------------------------------------------------
// res[b*200+t] = sum_c (stu-nk)*nk*W_out[c] + b_out ; one wave per row.
// ---------------------------------------------------------------------------
__global__ void res_kernel(const float* __restrict__ stu, const float* __restrict__ nk,
                           const float* __restrict__ Wout, const float* __restrict__ bout,
                           float* __restrict__ res) {
  const int row = blockIdx.x * 4 + (threadIdx.x >> 6);
  const int lane = threadIdx.x & 63;
  const float* sp = stu + (size_t)row * 256;
  const float* np = nk + (size_t)row * 256;
  float s = 0.0f;
#pragma unroll
  for (int j = 0; j < 4; ++j) {
    const int c = j * 64 + lane;
    const float nv = np[c];
    s += (sp[c] - nv) * nv * Wout[c];
  }
#pragma unroll
  for (int o = 32; o > 0; o >>= 1) s += __shfl_down(s, o, 64);
  if (lane == 0) res[row] = s + bout[0];
}

// ---------------------------------------------------------------------------
extern "C" void kernel_launch(void* const* d_in, const int* in_sizes, int n_in,
                              void* d_out, int out_size, void* d_ws, size_t ws_size,
                              hipStream_t stream) {
  const float* q_hot = (const float*)d_in[0];
  const int* result = (const int*)d_in[1];
  const float* next_q = (const float*)d_in[2];
  // d_in[3] = concept_num (unused, compile-time constant 256)
  const float* W_kc = (const float*)d_in[4];
  const float* b_kc = (const float*)d_in[5];
  const float* W_ih = (const float*)d_in[6];
  const float* W_hh = (const float*)d_in[7];
  const float* b_ih = (const float*)d_in[8];
  const float* b_hh = (const float*)d_in[9];
  const float* W_state = (const float*)d_in[10];
  const float* b_state = (const float*)d_in[11];
  const float* W_out = (const float*)d_in[12];
  const float* b_out = (const float*)d_in[13];

  float* out_res = (float*)d_out;       // 12800 fp32
  float* out_stu = out_res + 12800;     // 12800*256 fp32

  char* ws = (char*)d_ws;
  u16* kcv = (u16*)(ws);                        // 12800*512 bf16  = 13,107,200 B
  float* nk = (float*)(ws + 13107200);          // 12800*256 fp32  = 13,107,200 B
  u16* hseq = (u16*)(ws + 26214400);            // 201*65536 bf16  = 26,345,472 B
  u16* Whh_bf = (u16*)(ws + 52559872);          // 4096*1024 bf16  =  8,388,608 B
  u16* Wih_bf = (u16*)(ws + 60948480);          // 4096*512 bf16   =  4,194,304 B
  u16* Wkc_bf = (u16*)(ws + 65142784);          // 256*1024 bf16   =    524,288 B
  u16* Wst_bf = (u16*)(ws + 65667072);          // 256*1024 bf16   =    524,288 B
  unsigned* flags = (unsigned*)(ws + 66191360); // 256 u32 = 1024 B
  u16* gx = (u16*)(ws + 66192384);              // 12800*4096 bf16 = 104,857,600 B
  // q_bf/nq_bf alias the gx region (dead before gx is written)
  u16* q_bf = gx;                               // 12800*1024 bf16 = 26,214,400 B
  u16* nq_bf = gx + 13107200;                   // 12800*1024 bf16
  // total ws footprint: 171,049,984 B

  // fp32 -> bf16 conversions
  cvt_kernel<<<dim3(12800), 256, 0, stream>>>(q_hot, q_bf);
  cvt_kernel<<<dim3(12800), 256, 0, stream>>>(next_q, nq_bf);
  cvt_kernel<<<dim3(256), 256, 0, stream>>>(W_kc, Wkc_bf);
  cvt_kernel<<<dim3(2048), 256, 0, stream>>>(W_ih, Wih_bf);
  cvt_kernel<<<dim3(4096), 256, 0, stream>>>(W_hh, Whh_bf);
  cvt_kernel<<<dim3(256), 256, 0, stream>>>(W_state, Wst_bf);

  init_kernel<<<dim3(64), 256, 0, stream>>>(hseq, flags);
  gemm_bt<EpiKcVec><<<dim3(100, 2), 256, 0, stream>>>(q_bf, Wkc_bf, 12800, 256, 1024,
                                                      EpiKcVec{b_kc, result, kcv});
  gemm_bt<EpiNk><<<dim3(100, 2), 256, 0, stream>>>(nq_bf, Wkc_bf, 12800, 256, 1024,
                                                   EpiNk{b_kc, nk});
  gemm_bt<EpiGx><<<dim3(100, 32), 256, 0, stream>>>(kcv, Wih_bf, 12800, 4096, 512,
                                                    EpiGx{b_ih, b_hh, gx});
  lstm_scan<<<dim3(256), 256, 0, stream>>>(Whh_bf, gx, hseq, flags);
  gemm_bt<EpiStu><<<dim3(100, 2), 256, 0, stream>>>(hseq + 65536, Wst_bf, 12800, 256, 1024,
                                                    EpiStu{b_state, out_stu});
  res_kernel<<<dim3(3200), 256, 0, stream>>>(out_stu, nk, W_out, b_out, out_res);
}

// Round 5
// 1331.095 us; speedup vs baseline: 5.1079x; 3.7659x over previous
//
#include <hip/hip_runtime.h>
#include <math.h>

// ---------------------------------------------------------------------------
// RNN knowledge-tracing model, MI355X (gfx950).
// B=64, T=200, SKILLS=1024, C=256, H=1024.  ALL external I/O is fp32.
// Internal compute uses bf16 MFMA with fp32 accumulation.
// Round 5 changes vs round 4:
//   * FIX: h staging chunk->LDS map used >>7/&127 (16B-chunk counts) for 8B
//     u64 chunks; must be >>8/&255 (256 u64 per 1024-col row). Round-4's
//     absmax 0.109 came from this garbled staging (+ masked LDS overflow).
//   * Publish h via atomic EXCHANGE with used return (sc0 form): returned
//     atomics execute at the coherence point, so vmcnt(0) on the returns
//     guarantees h is globally visible before the flag store (closes the
//     store-ack != visibility hole of plain stores).
// Fence-free otherwise: no threadfence/acquire anywhere in the scan loop
// (the L2 wbl2/inv walks were the 23-32 us/step wall of rounds 2-3).
// ---------------------------------------------------------------------------

typedef unsigned short u16;
typedef unsigned long long u64;
typedef __bf16 bf16x8 __attribute__((ext_vector_type(8)));
typedef float floatx4 __attribute__((ext_vector_type(4)));

__device__ __forceinline__ float bf2f(u16 h) {
  unsigned int u = ((unsigned int)h) << 16;
  float f;
  __builtin_memcpy(&f, &u, 4);
  return f;
}
__device__ __forceinline__ u16 f2bf(float f) {
  unsigned int u;
  __builtin_memcpy(&u, &f, 4);
  u += 0x7FFFu + ((u >> 16) & 1u);  // RNE
  return (u16)(u >> 16);
}
__device__ __forceinline__ float sigm(float x) { return 1.0f / (1.0f + __expf(-x)); }

// --- fp32 -> bf16 convert, float4 vectorized; exact grid (n % 1024 == 0) ---
__global__ void cvt_kernel(const float* __restrict__ in, u16* __restrict__ out) {
  const int i = blockIdx.x * 256 + threadIdx.x;
  const float4 v = ((const float4*)in)[i];
  ushort4 o;
  o.x = f2bf(v.x);
  o.y = f2bf(v.y);
  o.z = f2bf(v.z);
  o.w = f2bf(v.w);
  ((ushort4*)out)[i] = o;
}

// ---------------------------------------------------------------------------
// Generic 128x128-tile bf16 GEMM, C = A[M,K] @ B[N,K]^T, epilogue functor.
// ---------------------------------------------------------------------------
template <class Epi>
__global__ __launch_bounds__(256, 2) void gemm_bt(const u16* __restrict__ A,
                                                  const u16* __restrict__ B,
                                                  int M, int N, int K, Epi epi) {
  __shared__ u16 As[128 * 32];
  __shared__ u16 Bs[128 * 32];
  const int tid = threadIdx.x;
  const int w = tid >> 6, lane = tid & 63;
  const int wm = w & 1, wn = w >> 1;
  const int bm = blockIdx.x * 128, bn = blockIdx.y * 128;
  const int lrow = lane & 15, lk8 = (lane >> 4) * 8;
  const int srow = lane >> 2;        // staging: row within 16-row segment
  const int skc = (lane & 3) * 8;    // staging: k chunk (8 bf16 = 16B)

  floatx4 acc[4][4] = {};

  for (int k0 = 0; k0 < K; k0 += 32) {
#pragma unroll
    for (int r = 0; r < 2; ++r) {
      const int seg = w * 2 + r;  // 8 segments of 16 rows x 32 k
      const int row = seg * 16 + srow;
      __builtin_amdgcn_global_load_lds(
          (const __attribute__((address_space(1))) unsigned int*)(A + (size_t)(bm + row) * K + k0 + skc),
          (__attribute__((address_space(3))) unsigned int*)(As + seg * 512), 16, 0, 0);
      __builtin_amdgcn_global_load_lds(
          (const __attribute__((address_space(1))) unsigned int*)(B + (size_t)(bn + row) * K + k0 + skc),
          (__attribute__((address_space(3))) unsigned int*)(Bs + seg * 512), 16, 0, 0);
    }
    __syncthreads();

    bf16x8 af[4], bfr[4];
#pragma unroll
    for (int i = 0; i < 4; ++i) {
      af[i] = *(const bf16x8*)(As + (wm * 64 + i * 16 + lrow) * 32 + lk8);
      bfr[i] = *(const bf16x8*)(Bs + (wn * 64 + i * 16 + lrow) * 32 + lk8);
    }
#pragma unroll
    for (int i = 0; i < 4; ++i)
#pragma unroll
      for (int j = 0; j < 4; ++j)
        acc[i][j] = __builtin_amdgcn_mfma_f32_16x16x32_bf16(af[i], bfr[j], acc[i][j], 0, 0, 0);
    __syncthreads();
  }

  // C/D layout: col = lane&15, row = (lane>>4)*4 + reg  [verified m89/m91]
  const int rbase = bm + wm * 64 + (lane >> 4) * 4;
  const int cbase = bn + wn * 64 + lrow;
#pragma unroll
  for (int i = 0; i < 4; ++i)
#pragma unroll
    for (int j = 0; j < 4; ++j)
#pragma unroll
      for (int r = 0; r < 4; ++r)
        epi(rbase + i * 16 + r, cbase + j * 16, acc[i][j][r]);
}

// --- epilogues --------------------------------------------------------------
struct EpiKcVec {  // rows are b*200+t; scatter into [row][512] by result mask
  const float* bkc;
  const int* result;
  u16* kcv;
  __device__ void operator()(int row, int col, float v) const {
    v += bkc[col];
    const int off = (result[row] == 1) ? 0 : 256;
    const size_t base = (size_t)row * 512;
    kcv[base + off + col] = f2bf(v);
    kcv[base + (256 - off) + col] = 0;  // zero half
  }
};
struct EpiNk {
  const float* bkc;
  float* nk;
  __device__ void operator()(int row, int col, float v) const {
    nk[(size_t)row * 256 + col] = v + bkc[col];
  }
};
struct EpiGx {  // input row = b*200+t -> store t-major (t*64+b), bf16
  const float* bih;
  const float* bhh;
  u16* gx;
  __device__ void operator()(int row, int col, float v) const {
    v += bih[col] + bhh[col];
    const int b = row / 200, t = row - b * 200;
    gx[(size_t)(t * 64 + b) * 4096 + col] = f2bf(v);
  }
};
struct EpiStu {  // input row = t*64+b -> store fp32 at (b*200+t)*256+col
  const float* bst;
  float* out;
  __device__ void operator()(int row, int col, float v) const {
    v += bst[col];
    const int b = row & 63, t = row >> 6;
    out[(size_t)(b * 200 + t) * 256 + col] = v;
  }
};

// ---------------------------------------------------------------------------
// init: zero h frame 0 (64x1024 bf16 = 128KB) + 256 barrier flags
// ---------------------------------------------------------------------------
__global__ void init_kernel(u16* hseq, unsigned* flags) {
  const int i = blockIdx.x * 256 + threadIdx.x;  // 64 blocks -> 16384 threads
  ((u64*)hseq)[i] = 0ULL;
  if (blockIdx.x == 0) flags[threadIdx.x] = 0u;
}

// ---------------------------------------------------------------------------
// LSTM scan. 256 blocks = 4 batch-groups x 64 col-groups; block owns 16
// batches x 16 h-cols. Wave w (0..3) = gate w; its W_hh slice (16 rows x
// 1024 K) lives in registers as 32 MFMA B-fragments for the whole kernel.
//
// Fence-free h exchange (NO __threadfence / acquire anywhere in the loop):
//   publish: h tile -> LDS hbuf -> wave 0: 64 relaxed AGENT u64 atomic
//            EXCHANGES (returned atomics execute at the coherence point);
//            s_waitcnt vmcnt(0) on the returns -> lane 0 relaxed flag store.
//   wait:    wave 0 polls the 64 flags of ITS batch-group (independent
//            chains), relaxed loads, then __syncthreads.
//   consume: h[t] staged via relaxed AGENT u64 atomic loads (bypass stale
//            caches; proven to observe remote stores by round-3 flag polls).
// ---------------------------------------------------------------------------
__global__ __launch_bounds__(256, 1) void lstm_scan(const u16* __restrict__ Whh,
                                                    const u16* __restrict__ gx,
                                                    u16* __restrict__ hseq,
                                                    unsigned* __restrict__ flags) {
  __shared__ __align__(16) u16 Ab[16 * 1032];  // +8 pad: 2-way bank alias (free)
  __shared__ float gbuf[4 * 256];
  __shared__ __align__(16) u16 hbuf[256];
  const int tid = threadIdx.x;
  const int w = tid >> 6;         // gate index (torch order i,f,g,o)
  const int lane = tid & 63;
  const int lrow = lane & 15;
  const int lk8 = (lane >> 4) * 8;
  const int gb = blockIdx.x >> 6;
  const int gn = blockIdx.x & 63;
  const int bb = gb * 16;
  const int j0 = gn * 16;

  // B-fragments: W_hh[w*1024 + j0 + n][k], n = lane&15 -> 128 VGPRs, loaded once
  bf16x8 bfrag[32];
  {
    const u16* wp = Whh + (size_t)(w * 1024 + j0 + lrow) * 1024 + lk8;
#pragma unroll
    for (int ks = 0; ks < 32; ++ks) bfrag[ks] = *(const bf16x8*)(wp + ks * 32);
  }

  float c_state = 0.0f;
  const int um = tid >> 4, un = tid & 15;  // update-phase (batch, col) mapping

  // gx fetch: 4 values/thread (batch rows (lane>>4)*4+r, gate w, col j0+lrow)
  const u16* gxb = gx + (size_t)(bb + (lane >> 4) * 4) * 4096 + w * 1024 + j0 + lrow;
  u16 gcur[4];
  {
    const u16* gp = gxb;  // t = 0
    gcur[0] = gp[0];
    gcur[1] = gp[4096];
    gcur[2] = gp[8192];
    gcur[3] = gp[12288];
  }

  for (int t = 0; t < 200; ++t) {
    // stage h[t] rows bb..bb+15 (32KB contiguous) via agent-relaxed u64 loads.
    // 4096 u64 chunks; 256 u64 per 1024-col row -> row = ch>>8, col = (ch&255)*4.
    {
      const u64* hs = (const u64*)(hseq + (size_t)t * 65536 + (size_t)bb * 1024);
      u64 tmp[16];
#pragma unroll
      for (int jj = 0; jj < 16; ++jj)
        tmp[jj] = __hip_atomic_load(hs + jj * 256 + tid, __ATOMIC_RELAXED,
                                    __HIP_MEMORY_SCOPE_AGENT);
#pragma unroll
      for (int jj = 0; jj < 16; ++jj) {
        const int ch = jj * 256 + tid;          // 4096 u64 chunks
        const int row = ch >> 8;                // 256 u64 chunks per row
        const int cc = (ch & 255) * 4;          // u16 col within row
        *(u64*)(Ab + row * 1032 + cc) = tmp[jj];
      }
    }
    __syncthreads();

    // acc init = gx (includes b_ih+b_hh); D layout col=lane&15, row=(lane>>4)*4+r
    floatx4 acc;
    acc[0] = bf2f(gcur[0]);
    acc[1] = bf2f(gcur[1]);
    acc[2] = bf2f(gcur[2]);
    acc[3] = bf2f(gcur[3]);
#pragma unroll
    for (int ks = 0; ks < 32; ++ks) {
      bf16x8 a = *(const bf16x8*)(Ab + lrow * 1032 + ks * 32 + lk8);
      acc = __builtin_amdgcn_mfma_f32_16x16x32_bf16(a, bfrag[ks], acc, 0, 0, 0);
    }
    {
      const int mrow = (lane >> 4) * 4;
#pragma unroll
      for (int r = 0; r < 4; ++r) gbuf[w * 256 + (mrow + r) * 16 + lrow] = acc[r];
    }
    __syncthreads();

    const float gi = gbuf[tid];
    const float gf = gbuf[256 + tid];
    const float gg = gbuf[512 + tid];
    const float go = gbuf[768 + tid];
    c_state = sigm(gf) * c_state + sigm(gi) * tanhf(gg);
    const float h = sigm(go) * tanhf(c_state);
    hbuf[um * 16 + un] = f2bf(h);
    __syncthreads();

    // ---- publish: wave 0 pushes the 16x16 tile via returning exchanges ----
    if (tid < 64) {
      const int row = lane >> 2, ck = lane & 3;  // 4 u64 per 16-col row
      const u64 v = *(const u64*)(hbuf + row * 16 + ck * 4);
      u64 old = __hip_atomic_exchange(
          (u64*)(hseq + (size_t)(t + 1) * 65536 + (size_t)(bb + row) * 1024 + j0 + ck * 4),
          v, __ATOMIC_RELAXED, __HIP_MEMORY_SCOPE_AGENT);
      asm volatile("" ::"v"(old));                      // force sc0 (returning) form
      asm volatile("s_waitcnt vmcnt(0)" ::: "memory");  // returns back => h at IC
      if (lane == 0)
        __hip_atomic_store(&flags[blockIdx.x], (unsigned)(t + 1), __ATOMIC_RELAXED,
                           __HIP_MEMORY_SCOPE_AGENT);
    }

    // ---- prefetch gx for t+1 while the barrier resolves ----
    if (t < 199) {
      const u16* gp = gxb + (size_t)(t + 1) * 64 * 4096;
      gcur[0] = gp[0];
      gcur[1] = gp[4096];
      gcur[2] = gp[8192];
      gcur[3] = gp[12288];
    }

    // ---- wait: wave 0 polls own batch-group's 64 flags (1 per lane) ----
    if (tid < 64) {
      const unsigned tgt = (unsigned)(t + 1);
      const unsigned* gf64 = &flags[gb * 64 + lane];
      for (;;) {
        const unsigned v = __hip_atomic_load(gf64, __ATOMIC_RELAXED,
                                             __HIP_MEMORY_SCOPE_AGENT);
        if (__all(v >= tgt)) break;
        __builtin_amdgcn_s_sleep(1);
      }
    }
    __syncthreads();
  }
}

// ---------------------------------------------------------------------------
// res[b*200+t] = sum_c (stu-nk)*nk*W_out[c] + b_out ; one wave per row.
// ---------------------------------------------------------------------------
__global__ void res_kernel(const float* __restrict__ stu, const float* __restrict__ nk,
                           const float* __restrict__ Wout, const float* __restrict__ bout,
                           float* __restrict__ res) {
  const int row = blockIdx.x * 4 + (threadIdx.x >> 6);
  const int lane = threadIdx.x & 63;
  const float* sp = stu + (size_t)row * 256;
  const float* np = nk + (size_t)row * 256;
  float s = 0.0f;
#pragma unroll
  for (int j = 0; j < 4; ++j) {
    const int c = j * 64 + lane;
    const float nv = np[c];
    s += (sp[c] - nv) * nv * Wout[c];
  }
#pragma unroll
  for (int o = 32; o > 0; o >>= 1) s += __shfl_down(s, o, 64);
  if (lane == 0) res[row] = s + bout[0];
}

// ---------------------------------------------------------------------------
extern "C" void kernel_launch(void* const* d_in, const int* in_sizes, int n_in,
                              void* d_out, int out_size, void* d_ws, size_t ws_size,
                              hipStream_t stream) {
  const float* q_hot = (const float*)d_in[0];
  const int* result = (const int*)d_in[1];
  const float* next_q = (const float*)d_in[2];
  // d_in[3] = concept_num (unused, compile-time constant 256)
  const float* W_kc = (const float*)d_in[4];
  const float* b_kc = (const float*)d_in[5];
  const float* W_ih = (const float*)d_in[6];
  const float* W_hh = (const float*)d_in[7];
  const float* b_ih = (const float*)d_in[8];
  const float* b_hh = (const float*)d_in[9];
  const float* W_state = (const float*)d_in[10];
  const float* b_state = (const float*)d_in[11];
  const float* W_out = (const float*)d_in[12];
  const float* b_out = (const float*)d_in[13];

  float* out_res = (float*)d_out;       // 12800 fp32
  float* out_stu = out_res + 12800;     // 12800*256 fp32

  char* ws = (char*)d_ws;
  u16* kcv = (u16*)(ws);                        // 12800*512 bf16  = 13,107,200 B
  float* nk = (float*)(ws + 13107200);          // 12800*256 fp32  = 13,107,200 B
  u16* hseq = (u16*)(ws + 26214400);            // 201*65536 bf16  = 26,345,472 B
  u16* Whh_bf = (u16*)(ws + 52559872);          // 4096*1024 bf16  =  8,388,608 B
  u16* Wih_bf = (u16*)(ws + 60948480);          // 4096*512 bf16   =  4,194,304 B
  u16* Wkc_bf = (u16*)(ws + 65142784);          // 256*1024 bf16   =    524,288 B
  u16* Wst_bf = (u16*)(ws + 65667072);          // 256*1024 bf16   =    524,288 B
  unsigned* flags = (unsigned*)(ws + 66191360); // 256 u32 = 1024 B
  u16* gx = (u16*)(ws + 66192384);              // 12800*4096 bf16 = 104,857,600 B
  // q_bf/nq_bf alias the gx region (dead before gx is written)
  u16* q_bf = gx;                               // 12800*1024 bf16 = 26,214,400 B
  u16* nq_bf = gx + 13107200;                   // 12800*1024 bf16
  // total ws footprint: 171,049,984 B

  // fp32 -> bf16 conversions
  cvt_kernel<<<dim3(12800), 256, 0, stream>>>(q_hot, q_bf);
  cvt_kernel<<<dim3(12800), 256, 0, stream>>>(next_q, nq_bf);
  cvt_kernel<<<dim3(256), 256, 0, stream>>>(W_kc, Wkc_bf);
  cvt_kernel<<<dim3(2048), 256, 0, stream>>>(W_ih, Wih_bf);
  cvt_kernel<<<dim3(4096), 256, 0, stream>>>(W_hh, Whh_bf);
  cvt_kernel<<<dim3(256), 256, 0, stream>>>(W_state, Wst_bf);

  init_kernel<<<dim3(64), 256, 0, stream>>>(hseq, flags);
  gemm_bt<EpiKcVec><<<dim3(100, 2), 256, 0, stream>>>(q_bf, Wkc_bf, 12800, 256, 1024,
                                                      EpiKcVec{b_kc, result, kcv});
  gemm_bt<EpiNk><<<dim3(100, 2), 256, 0, stream>>>(nq_bf, Wkc_bf, 12800, 256, 1024,
                                                   EpiNk{b_kc, nk});
  gemm_bt<EpiGx><<<dim3(100, 32), 256, 0, stream>>>(kcv, Wih_bf, 12800, 4096, 512,
                                                    EpiGx{b_ih, b_hh, gx});
  lstm_scan<<<dim3(256), 256, 0, stream>>>(Whh_bf, gx, hseq, flags);
  gemm_bt<EpiStu><<<dim3(100, 2), 256, 0, stream>>>(hseq + 65536, Wst_bf, 12800, 256, 1024,
                                                    EpiStu{b_state, out_stu});
  res_kernel<<<dim3(3200), 256, 0, stream>>>(out_stu, nk, W_out, b_out, out_res);
}